// Round 5
// baseline (594.126 us; speedup 1.0000x reference)
//
#include <hip/hip_runtime.h>
#include <hip/hip_bf16.h>

#define EPSF 1e-5f

static constexpr int NGRAPH = 64;
static constexpr int HBA = 512;  // nodes per dst-range
static constexpr int SH = 9;     // log2(HBA)
static constexpr int GB = 256;   // blocks for count/scatter passes
static constexpr int CH = 6;     // chunks per range for bucket scans

__device__ __forceinline__ void gAtomicAdd(float* p, float v) {
  unsafeAtomicAdd(p, v);  // native global_atomic_add_f32 on gfx950
}

// ---------- BN0 stats over x [N,4]: sum[4], sumsq[4] -> stats[8] ----------
__global__ void k_bnstats(const float4* __restrict__ x, int N,
                          float* __restrict__ stats) {
  float s[4] = {0, 0, 0, 0}, q[4] = {0, 0, 0, 0};
  for (int i = blockIdx.x * blockDim.x + threadIdx.x; i < N;
       i += gridDim.x * blockDim.x) {
    float4 v = x[i];
    s[0] += v.x; q[0] += v.x * v.x;
    s[1] += v.y; q[1] += v.y * v.y;
    s[2] += v.z; q[2] += v.z * v.z;
    s[3] += v.w; q[3] += v.w * v.w;
  }
#pragma unroll
  for (int o = 32; o > 0; o >>= 1) {
#pragma unroll
    for (int k = 0; k < 4; k++) {
      s[k] += __shfl_down(s[k], o);
      q[k] += __shfl_down(q[k], o);
    }
  }
  if ((threadIdx.x & 63) == 0) {
#pragma unroll
    for (int k = 0; k < 4; k++) {
      gAtomicAdd(&stats[k], s[k]);
      gAtomicAdd(&stats[4 + k], q[k]);
    }
  }
}

// ---------- bucket count: counts[g*256 + b] (transposed, coalesced) --------
__global__ void k_bcount(const int* __restrict__ ei, int E, int chunk,
                         unsigned* __restrict__ counts) {
  __shared__ unsigned cnt[256];
  if (threadIdx.x < 256) cnt[threadIdx.x] = 0;
  __syncthreads();
  int g = blockIdx.x;
  int lo = g * chunk, hi = min(E, lo + chunk);
  for (int e = lo + threadIdx.x; e < hi; e += blockDim.x)
    atomicAdd(&cnt[ei[E + e] >> SH], 1u);
  __syncthreads();
  if (threadIdx.x < 256) counts[(size_t)g * 256 + threadIdx.x] = cnt[threadIdx.x];
}

// ---------- bucket offsets: exclusive prefix -------------------------------
__global__ void k_boffsets(const unsigned* __restrict__ counts, int RA, int E,
                           unsigned* __restrict__ bases,
                           unsigned* __restrict__ bucketStart) {
  __shared__ unsigned total[256];
  __shared__ unsigned start[257];
  int b = threadIdx.x;
  if (b < RA) {
    unsigned run = 0;
    for (int g = 0; g < GB; g++) {
      bases[(size_t)g * 256 + b] = run;
      run += counts[(size_t)g * 256 + b];
    }
    total[b] = run;
  }
  __syncthreads();
  if (b == 0) {
    unsigned s = 0;
    for (int i = 0; i < RA; i++) {
      start[i] = s;
      s += total[i];
    }
    start[RA] = (unsigned)E;
    for (int i = 0; i <= RA; i++) bucketStart[i] = start[i];
  }
  __syncthreads();
  if (b < RA) {
    unsigned s0 = start[b];
    for (int g = 0; g < GB; g++) bases[(size_t)g * 256 + b] += s0;
  }
}

// ---------- bucket scatter: bedges[pos] = (src<<9)|rel ---------------------
__global__ void k_bscatter(const int* __restrict__ ei, int E, int chunk,
                           const unsigned* __restrict__ bases,
                           unsigned* __restrict__ bedges) {
  __shared__ unsigned cursor[256];
  int g = blockIdx.x;
  if (threadIdx.x < 256)
    cursor[threadIdx.x] = bases[(size_t)g * 256 + threadIdx.x];
  __syncthreads();
  int lo = g * chunk, hi = min(E, lo + chunk);
  for (int e = lo + threadIdx.x; e < hi; e += blockDim.x) {
    int s = ei[e];
    int d = ei[E + e];
    int b = d >> SH;
    unsigned pos = atomicAdd(&cursor[b], 1u);
    bedges[pos] = ((unsigned)s << SH) | (unsigned)(d & (HBA - 1));
  }
}

// ---------- chunked degree hist over own bucket slice ----------------------
__global__ void k_hist(const unsigned* __restrict__ bedges,
                       const unsigned* __restrict__ bucketStart, int RA,
                       unsigned* __restrict__ phist) {
  __shared__ unsigned h[HBA];
  int t = threadIdx.x;
  for (int i = t; i < HBA; i += blockDim.x) h[i] = 0;
  __syncthreads();
  int r = blockIdx.x % RA, c = blockIdx.x / RA;
  int blo = bucketStart[r], bhi = bucketStart[r + 1];
  int clen = (bhi - blo + CH - 1) / CH;
  int lo = blo + c * clen, hi = min(bhi, lo + clen);
  for (int e = lo + t; e < hi; e += blockDim.x)
    atomicAdd(&h[bedges[e] & (HBA - 1)], 1u);
  __syncthreads();
  unsigned* out = phist + ((size_t)(c * RA + r) << SH);
  for (int i = t; i < HBA; i += blockDim.x) out[i] = h[i];
}

__device__ __forceinline__ void bn0_coefs(const float* __restrict__ stats,
                                          const float* __restrict__ g,
                                          const float* __restrict__ b,
                                          float Ninv, float* sc, float* sh) {
#pragma unroll
  for (int k = 0; k < 4; k++) {
    float mu = stats[k] * Ninv;
    float var = stats[4 + k] * Ninv - mu * mu;
    var = var < 0.f ? 0.f : var;
    float s = g[k] / sqrtf(var + EPSF);
    sc[k] = s;
    sh[k] = b[k] - mu * s;
  }
}

// ---------- flat node prep: deg -> dinv; pk = {xz(16B), dinv, ...} 32B -----
__global__ void k_prep(const unsigned* __restrict__ phist,
                       const float4* __restrict__ x, int N, int RA,
                       const float* __restrict__ stats,
                       const float* __restrict__ bn0g,
                       const float* __restrict__ bn0b, float Ninv,
                       float4* __restrict__ pk) {
  int v = blockIdx.x * blockDim.x + threadIdx.x;
  if (v >= N) return;
  int r = v >> SH, t = v & (HBA - 1);
  unsigned deg = 0;
#pragma unroll
  for (int c = 0; c < CH; c++) deg += phist[((size_t)(c * RA + r) << SH) + t];
  float sc[4], sh[4];
  bn0_coefs(stats, bn0g, bn0b, Ninv, sc, sh);
  float dv = rsqrtf((float)deg + 1.0f);
  float4 xv = x[v];
  float4 z;
  z.x = dv * (xv.x * sc[0] + sh[0]);
  z.y = dv * (xv.y * sc[1] + sh[1]);
  z.z = dv * (xv.z * sc[2] + sh[2]);
  z.w = dv * (xv.w * sc[3] + sh[3]);
  pk[2 * (size_t)v] = z;
  pk[2 * (size_t)v + 1] = make_float4(dv, 0.f, 0.f, 0.f);
}

// ---------- hop-1 chunked accumulate: bins {xz x4, dinv} by rel ------------
__global__ void k_acc1(const unsigned* __restrict__ bedges,
                       const unsigned* __restrict__ bucketStart, int RA,
                       const float4* __restrict__ pk,
                       float* __restrict__ pacc) {
  __shared__ float h[5 * HBA];
  int t = threadIdx.x;
  for (int i = t; i < 5 * HBA; i += blockDim.x) h[i] = 0.f;
  __syncthreads();
  int r = blockIdx.x % RA, c = blockIdx.x / RA;
  int blo = bucketStart[r], bhi = bucketStart[r + 1];
  int clen = (bhi - blo + CH - 1) / CH;
  int lo = blo + c * clen, hi = min(bhi, lo + clen);
  const float* pkf = (const float*)pk;
  for (int e = lo + t; e < hi; e += blockDim.x) {
    unsigned p = bedges[e];
    int rel = p & (HBA - 1);
    int s = p >> SH;
    float4 z = pk[2 * (size_t)s];
    float dvs = pkf[8 * (size_t)s + 4];
    atomicAdd(&h[rel], z.x);
    atomicAdd(&h[HBA + rel], z.y);
    atomicAdd(&h[2 * HBA + rel], z.z);
    atomicAdd(&h[3 * HBA + rel], z.w);
    atomicAdd(&h[4 * HBA + rel], dvs);
  }
  __syncthreads();
  float* out = pacc + (size_t)(c * RA + r) * (5 * HBA);
  for (int i = t; i < 5 * HBA; i += blockDim.x) out[i] = h[i];
}

// ---------- node reduce 1: p2 in-place into pk; node terms U/S/cnt ---------
__global__ void k_node1(const float* __restrict__ pacc,
                        const int* __restrict__ batch, int N, int RA,
                        float4* __restrict__ pk, float* __restrict__ U,
                        float* __restrict__ S, float* __restrict__ cnt) {
  __shared__ float lac[NGRAPH * 6];
  for (int i = threadIdx.x; i < NGRAPH * 6; i += blockDim.x) lac[i] = 0.f;
  __syncthreads();
  int v = blockIdx.x * blockDim.x + threadIdx.x;
  if (v < N) {
    int r = v >> SH, t = v & (HBA - 1);
    float a0 = 0, a1 = 0, a2 = 0, a3 = 0, asd = 0;
#pragma unroll
    for (int c = 0; c < CH; c++) {
      const float* b = pacc + (size_t)(c * RA + r) * (5 * HBA);
      a0 += b[t];
      a1 += b[HBA + t];
      a2 += b[2 * HBA + t];
      a3 += b[3 * HBA + t];
      asd += b[4 * HBA + t];
    }
    float4 z = pk[2 * (size_t)v];
    float dv = ((const float*)pk)[8 * (size_t)v + 4];
    float idg = dv * dv;
    float4 pv;
    pv.x = idg * (a0 + z.x);
    pv.y = idg * (a1 + z.y);
    pv.z = idg * (a2 + z.z);
    pv.w = idg * (a3 + z.w);
    int g = batch[v];
    pk[2 * (size_t)v] = pv;
    pk[2 * (size_t)v + 1] = make_float4(dv, (float)g, 0.f, 0.f);
    int g6 = g * 6;
    atomicAdd(&lac[g6 + 0], dv * pv.x);
    atomicAdd(&lac[g6 + 1], dv * pv.y);
    atomicAdd(&lac[g6 + 2], dv * pv.z);
    atomicAdd(&lac[g6 + 3], dv * pv.w);
    atomicAdd(&lac[g6 + 4], idg + dv * asd);  // sigma: self + edge part
    atomicAdd(&lac[g6 + 5], 1.0f);
  }
  __syncthreads();
  if (threadIdx.x < NGRAPH) {
    int t = threadIdx.x;
    gAtomicAdd(&U[t * 4 + 0], lac[t * 6 + 0]);
    gAtomicAdd(&U[t * 4 + 1], lac[t * 6 + 1]);
    gAtomicAdd(&U[t * 4 + 2], lac[t * 6 + 2]);
    gAtomicAdd(&U[t * 4 + 3], lac[t * 6 + 3]);
    gAtomicAdd(&S[t], lac[t * 6 + 4]);
    gAtomicAdd(&cnt[t], lac[t * 6 + 5]);
  }
}

// ---------- hop-2 chunked accumulate: bins t2[d] += p2[s] ------------------
__global__ void k_acc2(const unsigned* __restrict__ bedges,
                       const unsigned* __restrict__ bucketStart, int RA,
                       const float4* __restrict__ pk,
                       float* __restrict__ pacc) {
  __shared__ float h[4 * HBA];
  int t = threadIdx.x;
  for (int i = t; i < 4 * HBA; i += blockDim.x) h[i] = 0.f;
  __syncthreads();
  int r = blockIdx.x % RA, c = blockIdx.x / RA;
  int blo = bucketStart[r], bhi = bucketStart[r + 1];
  int clen = (bhi - blo + CH - 1) / CH;
  int lo = blo + c * clen, hi = min(bhi, lo + clen);
  for (int e = lo + t; e < hi; e += blockDim.x) {
    unsigned p = bedges[e];
    int rel = p & (HBA - 1);
    int s = p >> SH;
    float4 pv = pk[2 * (size_t)s];
    atomicAdd(&h[rel], pv.x);
    atomicAdd(&h[HBA + rel], pv.y);
    atomicAdd(&h[2 * HBA + rel], pv.z);
    atomicAdd(&h[3 * HBA + rel], pv.w);
  }
  __syncthreads();
  float* out = pacc + (size_t)(c * RA + r) * (4 * HBA);
  for (int i = t; i < 4 * HBA; i += blockDim.x) out[i] = h[i];
}

// ---------- node reduce 2: U[g(d)] += dinv_d * t2[d] -----------------------
__global__ void k_node2(const float* __restrict__ pacc, int N, int RA,
                        const float4* __restrict__ pk, float* __restrict__ U) {
  __shared__ float lac[NGRAPH * 4];
  for (int i = threadIdx.x; i < NGRAPH * 4; i += blockDim.x) lac[i] = 0.f;
  __syncthreads();
  int v = blockIdx.x * blockDim.x + threadIdx.x;
  if (v < N) {
    int r = v >> SH, t = v & (HBA - 1);
    float t0 = 0, t1 = 0, t2 = 0, t3 = 0;
#pragma unroll
    for (int c = 0; c < CH; c++) {
      const float* b = pacc + (size_t)(c * RA + r) * (4 * HBA);
      t0 += b[t];
      t1 += b[HBA + t];
      t2 += b[2 * HBA + t];
      t3 += b[3 * HBA + t];
    }
    float4 rec = pk[2 * (size_t)v + 1];  // {dinv, graph}
    float dv = rec.x;
    int g4 = (int)rec.y * 4;
    atomicAdd(&lac[g4 + 0], dv * t0);
    atomicAdd(&lac[g4 + 1], dv * t1);
    atomicAdd(&lac[g4 + 2], dv * t2);
    atomicAdd(&lac[g4 + 3], dv * t3);
  }
  __syncthreads();
  if (threadIdx.x < NGRAPH * 4) gAtomicAdd(&U[threadIdx.x], lac[threadIdx.x]);
}

// ---------- epilogue: g_raw = U@(W0W1)+S*(b0W1)+cnt*b1 -> BN -> MLP --------
__global__ void k_final(const float* __restrict__ U, const float* __restrict__ S,
                        const float* __restrict__ cnt,
                        const float* __restrict__ W0, const float* __restrict__ b0,
                        const float* __restrict__ W1, const float* __restrict__ b1,
                        const float* __restrict__ bn1g,
                        const float* __restrict__ bn1b,
                        const float* __restrict__ l0W, const float* __restrict__ l0b,
                        const float* __restrict__ l1W, const float* __restrict__ l1b,
                        const float* __restrict__ oW, const float* __restrict__ ob,
                        float* __restrict__ out) {
  __shared__ float sW01[4 * 64];
  __shared__ float sb01[64];
  __shared__ float sA[64 * 64];
  __shared__ float sB[64 * 64];
  __shared__ float sSc[64], sSh[64];
  int t = threadIdx.x;
  {
    int k = t >> 6, f = t & 63;
    float a = 0.f;
    for (int j = 0; j < 64; j++) a += W0[k * 64 + j] * W1[j * 64 + f];
    sW01[k * 64 + f] = a;
  }
  if (t < 64) {
    float a = 0.f;
    for (int j = 0; j < 64; j++) a += b0[j] * W1[j * 64 + t];
    sb01[t] = a;
  }
  __syncthreads();
  for (int idx = t; idx < 4096; idx += 256) {
    int G = idx >> 6, f = idx & 63;
    float v = cnt[G] * b1[f] + S[G] * sb01[f];
    v += U[G * 4 + 0] * sW01[0 * 64 + f];
    v += U[G * 4 + 1] * sW01[1 * 64 + f];
    v += U[G * 4 + 2] * sW01[2 * 64 + f];
    v += U[G * 4 + 3] * sW01[3 * 64 + f];
    sA[idx] = v;
  }
  __syncthreads();
  if (t < 64) {
    float mu = 0.f;
    for (int G = 0; G < 64; G++) mu += sA[G * 64 + t];
    mu *= (1.0f / 64.0f);
    float var = 0.f;
    for (int G = 0; G < 64; G++) {
      float d = sA[G * 64 + t] - mu;
      var += d * d;
    }
    var *= (1.0f / 64.0f);
    float s = bn1g[t] / sqrtf(var + EPSF);
    sSc[t] = s;
    sSh[t] = bn1b[t] - mu * s;
  }
  __syncthreads();
  for (int idx = t; idx < 4096; idx += 256) {
    int f = idx & 63;
    sA[idx] = sA[idx] * sSc[f] + sSh[f];
  }
  __syncthreads();
  for (int idx = t; idx < 4096; idx += 256) {
    int G = idx >> 6, f = idx & 63;
    float v = l0b[f];
    for (int j = 0; j < 64; j++) v += sA[G * 64 + j] * l0W[j * 64 + f];
    sB[idx] = v;
  }
  __syncthreads();
  for (int idx = t; idx < 4096; idx += 256) {
    int G = idx >> 6, f = idx & 63;
    float v = l1b[f];
    for (int j = 0; j < 64; j++) v += sB[G * 64 + j] * l1W[j * 64 + f];
    sA[idx] = v;
  }
  __syncthreads();
  if (t < 64) {
    float v = ob[0];
    for (int j = 0; j < 64; j++) v += sA[t * 64 + j] * oW[j];
    out[t] = v;
  }
}

extern "C" void kernel_launch(void* const* d_in, const int* in_sizes, int n_in,
                              void* d_out, int out_size, void* d_ws,
                              size_t ws_size, hipStream_t stream) {
  const float* x = (const float*)d_in[0];
  const int* ei = (const int*)d_in[1];
  const int* batch = (const int*)d_in[2];
  const float* bn0g = (const float*)d_in[3];
  const float* bn0b = (const float*)d_in[4];
  const float* W0 = (const float*)d_in[5];
  const float* b0 = (const float*)d_in[6];
  const float* W1 = (const float*)d_in[7];
  const float* b1 = (const float*)d_in[8];
  const float* bn1g = (const float*)d_in[9];
  const float* bn1b = (const float*)d_in[10];
  const float* l0W = (const float*)d_in[11];
  const float* l0b = (const float*)d_in[12];
  const float* l1W = (const float*)d_in[13];
  const float* l1b = (const float*)d_in[14];
  const float* oW = (const float*)d_in[15];
  const float* ob = (const float*)d_in[16];

  const int N = in_sizes[0] / 4;
  const int E = in_sizes[1] / 2;
  const int RA = (N + HBA - 1) >> SH;  // 196 for N=100000 (must be <=256)
  const int chunk = (E + GB - 1) / GB;

  size_t off = 0;
  auto alloc = [&](size_t nbytes) {
    size_t cur = (off + 63) & ~(size_t)63;
    off = cur + nbytes;
    return (void*)((char*)d_ws + cur);
  };
  // --- zeroed region first ---
  float* stats = (float*)alloc(8 * 4);
  float* U = (float*)alloc(NGRAPH * 4 * 4);
  float* S = (float*)alloc(NGRAPH * 4);
  float* cnt = (float*)alloc(NGRAPH * 4);
  const size_t zero_bytes = off;
  // --- persistent small ---
  unsigned* bucketStart = (unsigned*)alloc((size_t)(256 + 1) * 4);
  // --- node records (pk: {xz,dinv} then in-place {p2,dinv,graph}) ---
  float4* pk = (float4*)alloc((size_t)N * 32);
  // --- bucketed edges ---
  unsigned* bedges = (unsigned*)alloc((size_t)E * 4);
  // --- arena: counts+bases | phist | pacc1 | pacc2 (disjoint lifetimes) ---
  size_t arena_bytes = (size_t)CH * RA * HBA * 5 * 4;  // max user: pacc1
  char* arena = (char*)alloc(arena_bytes);
  unsigned* counts = (unsigned*)arena;                   // 256*GB*4
  unsigned* bases = (unsigned*)(arena + (size_t)256 * GB * 4);
  unsigned* phist = (unsigned*)arena;                    // CH*RA*512*4
  float* pacc = (float*)arena;                           // acc1 then acc2
  (void)ws_size;

  hipMemsetAsync(d_ws, 0, zero_bytes, stream);

  const float Ninv = 1.0f / (float)N;
  const int nodeGrid = (N + 255) / 256;
  k_bnstats<<<256, 256, 0, stream>>>((const float4*)x, N, stats);
  k_bcount<<<GB, 256, 0, stream>>>(ei, E, chunk, counts);
  k_boffsets<<<1, 256, 0, stream>>>(counts, RA, E, bases, bucketStart);
  k_bscatter<<<GB, 256, 0, stream>>>(ei, E, chunk, bases, bedges);
  k_hist<<<RA * CH, 512, 0, stream>>>(bedges, bucketStart, RA, phist);
  k_prep<<<nodeGrid, 256, 0, stream>>>(phist, (const float4*)x, N, RA, stats,
                                       bn0g, bn0b, Ninv, pk);
  k_acc1<<<RA * CH, 512, 0, stream>>>(bedges, bucketStart, RA, pk, pacc);
  k_node1<<<nodeGrid, 256, 0, stream>>>(pacc, batch, N, RA, pk, U, S, cnt);
  k_acc2<<<RA * CH, 512, 0, stream>>>(bedges, bucketStart, RA, pk, pacc);
  k_node2<<<nodeGrid, 256, 0, stream>>>(pacc, N, RA, pk, U);
  k_final<<<1, 256, 0, stream>>>(U, S, cnt, W0, b0, W1, b1, bn1g, bn1b, l0W,
                                 l0b, l1W, l1b, oW, ob, (float*)d_out);
}

// Round 6
// 455.778 us; speedup vs baseline: 1.3035x; 1.3035x over previous
//
#include <hip/hip_runtime.h>
#include <hip/hip_bf16.h>

#define EPSF 1e-5f

static constexpr int NGRAPH = 64;
static constexpr int HBA = 512;  // nodes per dst-range
static constexpr int SH = 9;     // log2(HBA)
static constexpr int GB = 256;   // blocks for count/scatter passes
static constexpr int CH = 6;     // chunks per range for bucket scans
static constexpr int NBLK = 128; // blocks for node1/node2 (partial-write)
static constexpr int BNB = 64;   // blocks for bnstats partials

// ---------- BN0 stats partials: 64 blocks x 8 floats (NO global atomics) ---
__global__ void k_bnstats(const float4* __restrict__ x, int N,
                          float* __restrict__ bnpart) {
  float s[4] = {0, 0, 0, 0}, q[4] = {0, 0, 0, 0};
  for (int i = blockIdx.x * blockDim.x + threadIdx.x; i < N;
       i += gridDim.x * blockDim.x) {
    float4 v = x[i];
    s[0] += v.x; q[0] += v.x * v.x;
    s[1] += v.y; q[1] += v.y * v.y;
    s[2] += v.z; q[2] += v.z * v.z;
    s[3] += v.w; q[3] += v.w * v.w;
  }
#pragma unroll
  for (int o = 32; o > 0; o >>= 1) {
#pragma unroll
    for (int k = 0; k < 4; k++) {
      s[k] += __shfl_down(s[k], o);
      q[k] += __shfl_down(q[k], o);
    }
  }
  __shared__ float red[4][8];
  int w = threadIdx.x >> 6;
  if ((threadIdx.x & 63) == 0) {
#pragma unroll
    for (int k = 0; k < 4; k++) {
      red[w][k] = s[k];
      red[w][4 + k] = q[k];
    }
  }
  __syncthreads();
  if (threadIdx.x < 8) {
    float a = red[0][threadIdx.x] + red[1][threadIdx.x] +
              red[2][threadIdx.x] + red[3][threadIdx.x];
    bnpart[blockIdx.x * 8 + threadIdx.x] = a;
  }
}

// ---------- bucket count: counts[g*256 + b] (transposed, coalesced) --------
__global__ void k_bcount(const int* __restrict__ ei, int E, int chunk,
                         unsigned* __restrict__ counts) {
  __shared__ unsigned cnt[256];
  if (threadIdx.x < 256) cnt[threadIdx.x] = 0;
  __syncthreads();
  int g = blockIdx.x;
  int lo = g * chunk, hi = min(E, lo + chunk);
  for (int e = lo + threadIdx.x; e < hi; e += blockDim.x)
    atomicAdd(&cnt[ei[E + e] >> SH], 1u);
  __syncthreads();
  if (threadIdx.x < 256) counts[(size_t)g * 256 + threadIdx.x] = cnt[threadIdx.x];
}

// ---------- bucket offsets + BN0 stats reduce ------------------------------
__global__ void k_boffsets(const unsigned* __restrict__ counts, int RA, int E,
                           const float* __restrict__ bnpart,
                           unsigned* __restrict__ bases,
                           unsigned* __restrict__ bucketStart,
                           float* __restrict__ stats) {
  int b = threadIdx.x;
  if (b < 8) {  // reduce bnstats partials (independent of bucket work)
    float s = 0.f;
#pragma unroll 8
    for (int i = 0; i < BNB; i++) s += bnpart[i * 8 + b];
    stats[b] = s;
  }
  __shared__ unsigned total[256];
  __shared__ unsigned start[257];
  if (b < RA) {
    unsigned run = 0;
#pragma unroll 8
    for (int g = 0; g < GB; g++) {
      bases[(size_t)g * 256 + b] = run;
      run += counts[(size_t)g * 256 + b];
    }
    total[b] = run;
  }
  __syncthreads();
  if (b == 0) {
    unsigned s = 0;
    for (int i = 0; i < RA; i++) {
      start[i] = s;
      s += total[i];
    }
    start[RA] = (unsigned)E;
    for (int i = 0; i <= RA; i++) bucketStart[i] = start[i];
  }
  __syncthreads();
  if (b < RA) {
    unsigned s0 = start[b];
#pragma unroll 8
    for (int g = 0; g < GB; g++) bases[(size_t)g * 256 + b] += s0;
  }
}

// ---------- bucket scatter: bedges[pos] = (src<<9)|rel ---------------------
__global__ void k_bscatter(const int* __restrict__ ei, int E, int chunk,
                           const unsigned* __restrict__ bases,
                           unsigned* __restrict__ bedges) {
  __shared__ unsigned cursor[256];
  int g = blockIdx.x;
  if (threadIdx.x < 256)
    cursor[threadIdx.x] = bases[(size_t)g * 256 + threadIdx.x];
  __syncthreads();
  int lo = g * chunk, hi = min(E, lo + chunk);
  for (int e = lo + threadIdx.x; e < hi; e += blockDim.x) {
    int s = ei[e];
    int d = ei[E + e];
    int b = d >> SH;
    unsigned pos = atomicAdd(&cursor[b], 1u);
    bedges[pos] = ((unsigned)s << SH) | (unsigned)(d & (HBA - 1));
  }
}

// ---------- chunked degree hist over own bucket slice ----------------------
__global__ void k_hist(const unsigned* __restrict__ bedges,
                       const unsigned* __restrict__ bucketStart, int RA,
                       unsigned* __restrict__ phist) {
  __shared__ unsigned h[HBA];
  int t = threadIdx.x;
  for (int i = t; i < HBA; i += blockDim.x) h[i] = 0;
  __syncthreads();
  int r = blockIdx.x % RA, c = blockIdx.x / RA;
  int blo = bucketStart[r], bhi = bucketStart[r + 1];
  int clen = (bhi - blo + CH - 1) / CH;
  int lo = blo + c * clen, hi = min(bhi, lo + clen);
  for (int e = lo + t; e < hi; e += blockDim.x)
    atomicAdd(&h[bedges[e] & (HBA - 1)], 1u);
  __syncthreads();
  unsigned* out = phist + ((size_t)(c * RA + r) << SH);
  for (int i = t; i < HBA; i += blockDim.x) out[i] = h[i];
}

__device__ __forceinline__ void bn0_coefs(const float* __restrict__ stats,
                                          const float* __restrict__ g,
                                          const float* __restrict__ b,
                                          float Ninv, float* sc, float* sh) {
#pragma unroll
  for (int k = 0; k < 4; k++) {
    float mu = stats[k] * Ninv;
    float var = stats[4 + k] * Ninv - mu * mu;
    var = var < 0.f ? 0.f : var;
    float s = g[k] / sqrtf(var + EPSF);
    sc[k] = s;
    sh[k] = b[k] - mu * s;
  }
}

// ---------- flat node prep: deg -> dinv; pk = {xz(16B), dinv, ...} 32B -----
__global__ void k_prep(const unsigned* __restrict__ phist,
                       const float4* __restrict__ x, int N, int RA,
                       const float* __restrict__ stats,
                       const float* __restrict__ bn0g,
                       const float* __restrict__ bn0b, float Ninv,
                       float4* __restrict__ pk) {
  int v = blockIdx.x * blockDim.x + threadIdx.x;
  if (v >= N) return;
  int r = v >> SH, t = v & (HBA - 1);
  unsigned deg = 0;
#pragma unroll
  for (int c = 0; c < CH; c++) deg += phist[((size_t)(c * RA + r) << SH) + t];
  float sc[4], sh[4];
  bn0_coefs(stats, bn0g, bn0b, Ninv, sc, sh);
  float dv = rsqrtf((float)deg + 1.0f);
  float4 xv = x[v];
  float4 z;
  z.x = dv * (xv.x * sc[0] + sh[0]);
  z.y = dv * (xv.y * sc[1] + sh[1]);
  z.z = dv * (xv.z * sc[2] + sh[2]);
  z.w = dv * (xv.w * sc[3] + sh[3]);
  pk[2 * (size_t)v] = z;
  pk[2 * (size_t)v + 1] = make_float4(dv, 0.f, 0.f, 0.f);
}

// ---------- hop-1 chunked accumulate: bins {xz x4, dinv} by rel ------------
__global__ void k_acc1(const unsigned* __restrict__ bedges,
                       const unsigned* __restrict__ bucketStart, int RA,
                       const float4* __restrict__ pk,
                       float* __restrict__ pacc) {
  __shared__ float h[5 * HBA];
  int t = threadIdx.x;
  for (int i = t; i < 5 * HBA; i += blockDim.x) h[i] = 0.f;
  __syncthreads();
  int r = blockIdx.x % RA, c = blockIdx.x / RA;
  int blo = bucketStart[r], bhi = bucketStart[r + 1];
  int clen = (bhi - blo + CH - 1) / CH;
  int lo = blo + c * clen, hi = min(bhi, lo + clen);
  const float* pkf = (const float*)pk;
  for (int e = lo + t; e < hi; e += blockDim.x) {
    unsigned p = bedges[e];
    int rel = p & (HBA - 1);
    int s = p >> SH;
    float4 z = pk[2 * (size_t)s];
    float dvs = pkf[8 * (size_t)s + 4];
    atomicAdd(&h[rel], z.x);
    atomicAdd(&h[HBA + rel], z.y);
    atomicAdd(&h[2 * HBA + rel], z.z);
    atomicAdd(&h[3 * HBA + rel], z.w);
    atomicAdd(&h[4 * HBA + rel], dvs);
  }
  __syncthreads();
  float* out = pacc + (size_t)(c * RA + r) * (5 * HBA);
  for (int i = t; i < 5 * HBA; i += blockDim.x) out[i] = h[i];
}

// ---------- node reduce 1: p2 in-place into pk; per-block partials ---------
__global__ __launch_bounds__(256) void k_node1(
    const float* __restrict__ pacc, const int* __restrict__ batch, int N,
    int RA, float4* __restrict__ pk, float* __restrict__ part1) {
  __shared__ float lac[NGRAPH * 6];
  for (int i = threadIdx.x; i < NGRAPH * 6; i += blockDim.x) lac[i] = 0.f;
  __syncthreads();
  int total = gridDim.x * blockDim.x;
  int iters = (N + total - 1) / total;
  int v = blockIdx.x * blockDim.x + threadIdx.x;
  for (int it = 0; it < iters; ++it, v += total) {
    bool act = v < N;
    float u0 = 0, u1 = 0, u2 = 0, u3 = 0, sv = 0, cv = 0;
    int g = 0;
    if (act) {
      int r = v >> SH, t = v & (HBA - 1);
      float a0 = 0, a1 = 0, a2 = 0, a3 = 0, asd = 0;
#pragma unroll
      for (int c = 0; c < CH; c++) {
        const float* b = pacc + (size_t)(c * RA + r) * (5 * HBA);
        a0 += b[t];
        a1 += b[HBA + t];
        a2 += b[2 * HBA + t];
        a3 += b[3 * HBA + t];
        asd += b[4 * HBA + t];
      }
      float4 z = pk[2 * (size_t)v];
      float dv = ((const float*)pk)[8 * (size_t)v + 4];
      float idg = dv * dv;
      float4 pv;
      pv.x = idg * (a0 + z.x);
      pv.y = idg * (a1 + z.y);
      pv.z = idg * (a2 + z.z);
      pv.w = idg * (a3 + z.w);
      g = batch[v];
      pk[2 * (size_t)v] = pv;
      pk[2 * (size_t)v + 1] = make_float4(dv, (float)g, 0.f, 0.f);
      u0 = dv * pv.x; u1 = dv * pv.y; u2 = dv * pv.z; u3 = dv * pv.w;
      sv = idg + dv * asd;  // sigma: self + edge part
      cv = 1.0f;
    }
    if (__all(!act)) continue;
    int gf = __shfl(g, 0);
    bool uni = __all((!act) || (g == gf));
    if (uni) {  // wave-level shuffle reduce, 1 LDS atomic set per wave
#pragma unroll
      for (int o = 32; o > 0; o >>= 1) {
        u0 += __shfl_down(u0, o);
        u1 += __shfl_down(u1, o);
        u2 += __shfl_down(u2, o);
        u3 += __shfl_down(u3, o);
        sv += __shfl_down(sv, o);
        cv += __shfl_down(cv, o);
      }
      if ((threadIdx.x & 63) == 0) {
        int g6 = gf * 6;
        atomicAdd(&lac[g6 + 0], u0);
        atomicAdd(&lac[g6 + 1], u1);
        atomicAdd(&lac[g6 + 2], u2);
        atomicAdd(&lac[g6 + 3], u3);
        atomicAdd(&lac[g6 + 4], sv);
        atomicAdd(&lac[g6 + 5], cv);
      }
    } else if (act) {
      int g6 = g * 6;
      atomicAdd(&lac[g6 + 0], u0);
      atomicAdd(&lac[g6 + 1], u1);
      atomicAdd(&lac[g6 + 2], u2);
      atomicAdd(&lac[g6 + 3], u3);
      atomicAdd(&lac[g6 + 4], sv);
      atomicAdd(&lac[g6 + 5], cv);
    }
  }
  __syncthreads();
  float* out = part1 + (size_t)blockIdx.x * (NGRAPH * 6);
  for (int i = threadIdx.x; i < NGRAPH * 6; i += blockDim.x) out[i] = lac[i];
}

// ---------- hop-2 chunked accumulate: bins t2[d] += p2[s] ------------------
__global__ void k_acc2(const unsigned* __restrict__ bedges,
                       const unsigned* __restrict__ bucketStart, int RA,
                       const float4* __restrict__ pk,
                       float* __restrict__ pacc) {
  __shared__ float h[4 * HBA];
  int t = threadIdx.x;
  for (int i = t; i < 4 * HBA; i += blockDim.x) h[i] = 0.f;
  __syncthreads();
  int r = blockIdx.x % RA, c = blockIdx.x / RA;
  int blo = bucketStart[r], bhi = bucketStart[r + 1];
  int clen = (bhi - blo + CH - 1) / CH;
  int lo = blo + c * clen, hi = min(bhi, lo + clen);
  for (int e = lo + t; e < hi; e += blockDim.x) {
    unsigned p = bedges[e];
    int rel = p & (HBA - 1);
    int s = p >> SH;
    float4 pv = pk[2 * (size_t)s];
    atomicAdd(&h[rel], pv.x);
    atomicAdd(&h[HBA + rel], pv.y);
    atomicAdd(&h[2 * HBA + rel], pv.z);
    atomicAdd(&h[3 * HBA + rel], pv.w);
  }
  __syncthreads();
  float* out = pacc + (size_t)(c * RA + r) * (4 * HBA);
  for (int i = t; i < 4 * HBA; i += blockDim.x) out[i] = h[i];
}

// ---------- node reduce 2: per-block partials of U[g(d)] += dinv_d*t2[d] ---
__global__ __launch_bounds__(256) void k_node2(
    const float* __restrict__ pacc, int N, int RA,
    const float4* __restrict__ pk, float* __restrict__ part2) {
  __shared__ float lac[NGRAPH * 4];
  for (int i = threadIdx.x; i < NGRAPH * 4; i += blockDim.x) lac[i] = 0.f;
  __syncthreads();
  int total = gridDim.x * blockDim.x;
  int iters = (N + total - 1) / total;
  int v = blockIdx.x * blockDim.x + threadIdx.x;
  for (int it = 0; it < iters; ++it, v += total) {
    bool act = v < N;
    float u0 = 0, u1 = 0, u2 = 0, u3 = 0;
    int g = 0;
    if (act) {
      int r = v >> SH, t = v & (HBA - 1);
      float t0 = 0, t1 = 0, t2 = 0, t3 = 0;
#pragma unroll
      for (int c = 0; c < CH; c++) {
        const float* b = pacc + (size_t)(c * RA + r) * (4 * HBA);
        t0 += b[t];
        t1 += b[HBA + t];
        t2 += b[2 * HBA + t];
        t3 += b[3 * HBA + t];
      }
      float4 rec = pk[2 * (size_t)v + 1];  // {dinv, graph}
      float dv = rec.x;
      g = (int)rec.y;
      u0 = dv * t0; u1 = dv * t1; u2 = dv * t2; u3 = dv * t3;
    }
    if (__all(!act)) continue;
    int gf = __shfl(g, 0);
    bool uni = __all((!act) || (g == gf));
    if (uni) {
#pragma unroll
      for (int o = 32; o > 0; o >>= 1) {
        u0 += __shfl_down(u0, o);
        u1 += __shfl_down(u1, o);
        u2 += __shfl_down(u2, o);
        u3 += __shfl_down(u3, o);
      }
      if ((threadIdx.x & 63) == 0) {
        int g4 = gf * 4;
        atomicAdd(&lac[g4 + 0], u0);
        atomicAdd(&lac[g4 + 1], u1);
        atomicAdd(&lac[g4 + 2], u2);
        atomicAdd(&lac[g4 + 3], u3);
      }
    } else if (act) {
      int g4 = g * 4;
      atomicAdd(&lac[g4 + 0], u0);
      atomicAdd(&lac[g4 + 1], u1);
      atomicAdd(&lac[g4 + 2], u2);
      atomicAdd(&lac[g4 + 3], u3);
    }
  }
  __syncthreads();
  float* out = part2 + (size_t)blockIdx.x * (NGRAPH * 4);
  for (int i = threadIdx.x; i < NGRAPH * 4; i += blockDim.x) out[i] = lac[i];
}

// ---------- epilogue: reduce partials; g_raw -> BN -> MLP ------------------
__global__ void k_final(const float* __restrict__ part1,
                        const float* __restrict__ part2,
                        const float* __restrict__ W0, const float* __restrict__ b0,
                        const float* __restrict__ W1, const float* __restrict__ b1,
                        const float* __restrict__ bn1g,
                        const float* __restrict__ bn1b,
                        const float* __restrict__ l0W, const float* __restrict__ l0b,
                        const float* __restrict__ l1W, const float* __restrict__ l1b,
                        const float* __restrict__ oW, const float* __restrict__ ob,
                        float* __restrict__ out) {
  __shared__ float sP1[NGRAPH * 6];  // {U0..3, S, cnt} per graph (node terms)
  __shared__ float sU2[NGRAPH * 4];  // hop-2 U terms
  __shared__ float sW01[4 * 64];
  __shared__ float sb01[64];
  __shared__ float sA[64 * 64];
  __shared__ float sB[64 * 64];
  __shared__ float sSc[64], sSh[64];
  int t = threadIdx.x;
  // --- reduce per-block partials (NBLK x ...) ---
  for (int idx = t; idx < NGRAPH * 6; idx += 256) {
    float s = 0.f;
#pragma unroll 8
    for (int b = 0; b < NBLK; b++) s += part1[(size_t)b * (NGRAPH * 6) + idx];
    sP1[idx] = s;
  }
  for (int idx = t; idx < NGRAPH * 4; idx += 256) {
    float s = 0.f;
#pragma unroll 8
    for (int b = 0; b < NBLK; b++) s += part2[(size_t)b * (NGRAPH * 4) + idx];
    sU2[idx] = s;
  }
  {
    int k = t >> 6, f = t & 63;
    float a = 0.f;
    for (int j = 0; j < 64; j++) a += W0[k * 64 + j] * W1[j * 64 + f];
    sW01[k * 64 + f] = a;
  }
  if (t < 64) {
    float a = 0.f;
    for (int j = 0; j < 64; j++) a += b0[j] * W1[j * 64 + t];
    sb01[t] = a;
  }
  __syncthreads();
  for (int idx = t; idx < 4096; idx += 256) {
    int G = idx >> 6, f = idx & 63;
    float v = sP1[G * 6 + 5] * b1[f] + sP1[G * 6 + 4] * sb01[f];
    v += (sU2[G * 4 + 0] + sP1[G * 6 + 0]) * sW01[0 * 64 + f];
    v += (sU2[G * 4 + 1] + sP1[G * 6 + 1]) * sW01[1 * 64 + f];
    v += (sU2[G * 4 + 2] + sP1[G * 6 + 2]) * sW01[2 * 64 + f];
    v += (sU2[G * 4 + 3] + sP1[G * 6 + 3]) * sW01[3 * 64 + f];
    sA[idx] = v;
  }
  __syncthreads();
  if (t < 64) {
    float mu = 0.f;
    for (int G = 0; G < 64; G++) mu += sA[G * 64 + t];
    mu *= (1.0f / 64.0f);
    float var = 0.f;
    for (int G = 0; G < 64; G++) {
      float d = sA[G * 64 + t] - mu;
      var += d * d;
    }
    var *= (1.0f / 64.0f);
    float s = bn1g[t] / sqrtf(var + EPSF);
    sSc[t] = s;
    sSh[t] = bn1b[t] - mu * s;
  }
  __syncthreads();
  for (int idx = t; idx < 4096; idx += 256) {
    int f = idx & 63;
    sA[idx] = sA[idx] * sSc[f] + sSh[f];
  }
  __syncthreads();
  for (int idx = t; idx < 4096; idx += 256) {
    int G = idx >> 6, f = idx & 63;
    float v = l0b[f];
    for (int j = 0; j < 64; j++) v += sA[G * 64 + j] * l0W[j * 64 + f];
    sB[idx] = v;
  }
  __syncthreads();
  for (int idx = t; idx < 4096; idx += 256) {
    int G = idx >> 6, f = idx & 63;
    float v = l1b[f];
    for (int j = 0; j < 64; j++) v += sB[G * 64 + j] * l1W[j * 64 + f];
    sA[idx] = v;
  }
  __syncthreads();
  if (t < 64) {
    float v = ob[0];
    for (int j = 0; j < 64; j++) v += sA[t * 64 + j] * oW[j];
    out[t] = v;
  }
}

extern "C" void kernel_launch(void* const* d_in, const int* in_sizes, int n_in,
                              void* d_out, int out_size, void* d_ws,
                              size_t ws_size, hipStream_t stream) {
  const float* x = (const float*)d_in[0];
  const int* ei = (const int*)d_in[1];
  const int* batch = (const int*)d_in[2];
  const float* bn0g = (const float*)d_in[3];
  const float* bn0b = (const float*)d_in[4];
  const float* W0 = (const float*)d_in[5];
  const float* b0 = (const float*)d_in[6];
  const float* W1 = (const float*)d_in[7];
  const float* b1 = (const float*)d_in[8];
  const float* bn1g = (const float*)d_in[9];
  const float* bn1b = (const float*)d_in[10];
  const float* l0W = (const float*)d_in[11];
  const float* l0b = (const float*)d_in[12];
  const float* l1W = (const float*)d_in[13];
  const float* l1b = (const float*)d_in[14];
  const float* oW = (const float*)d_in[15];
  const float* ob = (const float*)d_in[16];

  const int N = in_sizes[0] / 4;
  const int E = in_sizes[1] / 2;
  const int RA = (N + HBA - 1) >> SH;  // 196 for N=100000 (must be <=256)
  const int chunk = (E + GB - 1) / GB;

  size_t off = 0;
  auto alloc = [&](size_t nbytes) {
    size_t cur = (off + 63) & ~(size_t)63;
    off = cur + nbytes;
    return (void*)((char*)d_ws + cur);
  };
  // all buffers fully written before read each call — no memset needed
  float* stats = (float*)alloc(8 * 4);
  float* bnpart = (float*)alloc((size_t)BNB * 8 * 4);
  unsigned* bucketStart = (unsigned*)alloc((size_t)(256 + 1) * 4);
  float* part1 = (float*)alloc((size_t)NBLK * NGRAPH * 6 * 4);
  float* part2 = (float*)alloc((size_t)NBLK * NGRAPH * 4 * 4);
  float4* pk = (float4*)alloc((size_t)N * 32);
  unsigned* bedges = (unsigned*)alloc((size_t)E * 4);
  // arena: counts+bases | phist | pacc1 | pacc2 (disjoint lifetimes)
  size_t arena_bytes = (size_t)CH * RA * HBA * 5 * 4;  // max user: pacc1
  char* arena = (char*)alloc(arena_bytes);
  unsigned* counts = (unsigned*)arena;  // 256*GB*4
  unsigned* bases = (unsigned*)(arena + (size_t)256 * GB * 4);
  unsigned* phist = (unsigned*)arena;   // CH*RA*512*4
  float* pacc = (float*)arena;          // acc1 then acc2
  (void)ws_size;

  const float Ninv = 1.0f / (float)N;
  const int nodeGrid = (N + 255) / 256;
  k_bnstats<<<BNB, 256, 0, stream>>>((const float4*)x, N, bnpart);
  k_bcount<<<GB, 256, 0, stream>>>(ei, E, chunk, counts);
  k_boffsets<<<1, 256, 0, stream>>>(counts, RA, E, bnpart, bases, bucketStart,
                                    stats);
  k_bscatter<<<GB, 256, 0, stream>>>(ei, E, chunk, bases, bedges);
  k_hist<<<RA * CH, 512, 0, stream>>>(bedges, bucketStart, RA, phist);
  k_prep<<<nodeGrid, 256, 0, stream>>>(phist, (const float4*)x, N, RA, stats,
                                       bn0g, bn0b, Ninv, pk);
  k_acc1<<<RA * CH, 512, 0, stream>>>(bedges, bucketStart, RA, pk, pacc);
  k_node1<<<NBLK, 256, 0, stream>>>(pacc, batch, N, RA, pk, part1);
  k_acc2<<<RA * CH, 512, 0, stream>>>(bedges, bucketStart, RA, pk, pacc);
  k_node2<<<NBLK, 256, 0, stream>>>(pacc, N, RA, pk, part2);
  k_final<<<1, 256, 0, stream>>>(part1, part2, W0, b0, W1, b1, bn1g, bn1b,
                                 l0W, l0b, l1W, l1b, oW, ob, (float*)d_out);
}